// Round 1
// baseline (159.618 us; speedup 1.0000x reference)
//
#include <hip/hip_runtime.h>
#include <hip/hip_bf16.h>
#include <cstdint>

#define HDIM 1024
#define BM 128
#define BN 64
#define BKK 32

typedef __attribute__((ext_vector_type(8))) __bf16 bf16x8;
typedef __attribute__((ext_vector_type(8))) unsigned short u16x8;
typedef __attribute__((ext_vector_type(4))) float f32x4;

static __device__ __forceinline__ unsigned short f2b(float f) {
    __hip_bfloat16 h = __float2bfloat16(f);
    return __builtin_bit_cast(unsigned short, h);
}

// fp32 -> bf16 pack (weights only; 12 MB in d_ws)
__global__ void __launch_bounds__(256) cvt_kernel(const float* __restrict__ src,
                                                  unsigned short* __restrict__ dst,
                                                  int n4) {
    int i = blockIdx.x * blockDim.x + threadIdx.x;
    if (i >= n4) return;
    float4 v = ((const float4*)src)[i];
    ushort4 o;
    o.x = f2b(v.x); o.y = f2b(v.y); o.z = f2b(v.z); o.w = f2b(v.w);
    ((ushort4*)dst)[i] = o;
}

// Fused GRU cell: per 128x64 output tile, accumulate
//   acc0 = x@Wr^T + h@Ur^T   acc1 = x@Wz^T + h@Uz^T
//   acc2 = x@Wn^T            acc3 = h@Un^T
// then gate epilogue.
__global__ void __launch_bounds__(256, 2)
gru_fused(const float* __restrict__ xg, const float* __restrict__ hg,
          const unsigned short* __restrict__ wih,
          const unsigned short* __restrict__ ur,
          const unsigned short* __restrict__ uz,
          const unsigned short* __restrict__ un,
          const float* __restrict__ bih, const float* __restrict__ bun,
          float* __restrict__ out) {
    // 40KB LDS: xs [128][32] bf16, hs [128][32], 6 weight tiles [64][32]
    __shared__ __align__(16) unsigned short smem[20480];
    unsigned short* xs  = smem;
    unsigned short* hs  = smem + 4096;
    unsigned short* wsm = smem + 8192;

    const int tid  = threadIdx.x;
    const int lane = tid & 63;
    const int wv   = tid >> 6;
    const int wm   = wv >> 1;      // wave M index (0..1)
    const int wn   = wv & 1;       // wave N index (0..1)
    const int lr   = lane & 15;
    const int ls   = lane >> 4;
    const int m0   = blockIdx.y * BM;
    const int n0   = blockIdx.x * BN;

    const unsigned short* wb[6] = {
        wih + (size_t)n0 * HDIM,
        wih + (size_t)(HDIM + n0) * HDIM,
        wih + (size_t)(2 * HDIM + n0) * HDIM,
        ur  + (size_t)n0 * HDIM,
        uz  + (size_t)n0 * HDIM,
        un  + (size_t)n0 * HDIM
    };

    f32x4 acc[4][4][2];
#pragma unroll
    for (int g = 0; g < 4; ++g)
#pragma unroll
        for (int mf = 0; mf < 4; ++mf)
#pragma unroll
            for (int nf = 0; nf < 2; ++nf)
                acc[g][mf][nf] = f32x4{0.f, 0.f, 0.f, 0.f};

    for (int kt = 0; kt < HDIM / BKK; ++kt) {
        const int k0 = kt * BKK;

        // --- async stage: 6 weight tiles (64 rows x 32 bf16) via global_load_lds w16
        {
            const int c  = wv * 64 + lane;   // chunk index within a matrix (0..255)
            const int r  = c >> 2;
            const int sl = c & 3;
#pragma unroll
            for (int mi = 0; mi < 6; ++mi) {
                const unsigned short* g = wb[mi] + (size_t)r * HDIM + k0 + sl * 8;
                unsigned short* l = wsm + mi * 2048 + wv * 512;  // wave-uniform dest
                __builtin_amdgcn_global_load_lds(
                    (const __attribute__((address_space(1))) void*)g,
                    (__attribute__((address_space(3))) void*)l, 16, 0, 0);
            }
        }

        // --- reg-stage x,h: fp32 load -> bf16 cvt -> linear b128 LDS writes
#pragma unroll
        for (int half = 0; half < 2; ++half) {
            const int ci = tid + half * 256;  // chunk 0..511 -> row=ci>>2, slot=ci&3
            const int r  = ci >> 2;
            const int sl = ci & 3;
            const float* gx = xg + (size_t)(m0 + r) * HDIM + k0 + sl * 8;
            const float* gh = hg + (size_t)(m0 + r) * HDIM + k0 + sl * 8;
            float4 x0 = ((const float4*)gx)[0];
            float4 x1 = ((const float4*)gx)[1];
            float4 h0 = ((const float4*)gh)[0];
            float4 h1 = ((const float4*)gh)[1];
            u16x8 px, ph;
            px[0] = f2b(x0.x); px[1] = f2b(x0.y); px[2] = f2b(x0.z); px[3] = f2b(x0.w);
            px[4] = f2b(x1.x); px[5] = f2b(x1.y); px[6] = f2b(x1.z); px[7] = f2b(x1.w);
            ph[0] = f2b(h0.x); ph[1] = f2b(h0.y); ph[2] = f2b(h0.z); ph[3] = f2b(h0.w);
            ph[4] = f2b(h1.x); ph[5] = f2b(h1.y); ph[6] = f2b(h1.z); ph[7] = f2b(h1.w);
            *(u16x8*)(xs + ci * 8) = px;
            *(u16x8*)(hs + ci * 8) = ph;
        }

        __syncthreads();  // drains vmcnt (global_load_lds) + lgkm (ds_write)

        // --- compute: 48 MFMA / wave / K-step
        bf16x8 ax[4], ah[4];
#pragma unroll
        for (int mf = 0; mf < 4; ++mf) {
            ax[mf] = *(const bf16x8*)(xs + (wm * 64 + mf * 16 + lr) * 32 + ls * 8);
            ah[mf] = *(const bf16x8*)(hs + (wm * 64 + mf * 16 + lr) * 32 + ls * 8);
        }
#pragma unroll
        for (int mi = 0; mi < 6; ++mi) {
            const unsigned short* wt = wsm + mi * 2048;
            bf16x8 b0 = *(const bf16x8*)(wt + (wn * 32 + lr) * 32 + ls * 8);
            bf16x8 b1 = *(const bf16x8*)(wt + (wn * 32 + 16 + lr) * 32 + ls * 8);
            const int g = (mi == 0 || mi == 3) ? 0 : (mi == 1 || mi == 4) ? 1 : (mi == 2) ? 2 : 3;
            const bf16x8* a = (mi < 3) ? ax : ah;
#pragma unroll
            for (int mf = 0; mf < 4; ++mf) {
                acc[g][mf][0] = __builtin_amdgcn_mfma_f32_16x16x32_bf16(a[mf], b0, acc[g][mf][0], 0, 0, 0);
                acc[g][mf][1] = __builtin_amdgcn_mfma_f32_16x16x32_bf16(a[mf], b1, acc[g][mf][1], 0, 0, 0);
            }
        }
        __syncthreads();  // all reads done before next stage overwrites
    }

    // --- epilogue: gates + output (C/D layout: col=lane&15, row=(lane>>4)*4+reg)
#pragma unroll
    for (int mf = 0; mf < 4; ++mf) {
#pragma unroll
        for (int nf = 0; nf < 2; ++nf) {
            const int gc = n0 + wn * 32 + nf * 16 + lr;
            const float br  = bih[gc];
            const float bz  = bih[HDIM + gc];
            const float bnx = bih[2 * HDIM + gc];
            const float bn2 = bun[gc];
            const f32x4 aR = acc[0][mf][nf];
            const f32x4 aZ = acc[1][mf][nf];
            const f32x4 aX = acc[2][mf][nf];
            const f32x4 aH = acc[3][mf][nf];
#pragma unroll
            for (int rr = 0; rr < 4; ++rr) {
                const int gr = m0 + wm * 64 + mf * 16 + ls * 4 + rr;
                const float rv = 1.f / (1.f + __expf(-(aR[rr] + br)));
                const float zv = 1.f / (1.f + __expf(-(aZ[rr] + bz)));
                const float nv = tanhf(aX[rr] + bnx + rv * (aH[rr] + bn2));
                const float hv = hg[(size_t)gr * HDIM + gc];
                out[(size_t)gr * HDIM + gc] = (1.f - zv) * nv + zv * hv;
            }
        }
    }
}

extern "C" void kernel_launch(void* const* d_in, const int* in_sizes, int n_in,
                              void* d_out, int out_size, void* d_ws, size_t ws_size,
                              hipStream_t stream) {
    const float* x   = (const float*)d_in[0];
    const float* h   = (const float*)d_in[1];
    const float* Wih = (const float*)d_in[2];
    const float* bih = (const float*)d_in[3];
    const float* Ur  = (const float*)d_in[4];
    const float* Uz  = (const float*)d_in[5];
    const float* Un  = (const float*)d_in[6];
    const float* bun = (const float*)d_in[7];
    float* out = (float*)d_out;

    unsigned short* wsp  = (unsigned short*)d_ws;
    unsigned short* wihb = wsp;                         // 3*1024*1024 bf16
    unsigned short* urb  = wihb + 3 * 1024 * 1024;
    unsigned short* uzb  = urb + 1024 * 1024;
    unsigned short* unb  = uzb + 1024 * 1024;           // total 12 MB

    cvt_kernel<<<3072, 256, 0, stream>>>(Wih, wihb, 3 * 1024 * 1024 / 4);
    cvt_kernel<<<1024, 256, 0, stream>>>(Ur, urb, 1024 * 1024 / 4);
    cvt_kernel<<<1024, 256, 0, stream>>>(Uz, uzb, 1024 * 1024 / 4);
    cvt_kernel<<<1024, 256, 0, stream>>>(Un, unb, 1024 * 1024 / 4);

    dim3 grid(HDIM / BN, 8192 / BM);  // (16, 64)
    gru_fused<<<grid, 256, 0, stream>>>(x, h, wihb, urb, uzb, unb, bih, bun, out);
}

// Round 2
// 142.427 us; speedup vs baseline: 1.1207x; 1.1207x over previous
//
#include <hip/hip_runtime.h>
#include <hip/hip_bf16.h>
#include <cstdint>

#define HDIM 1024
#define BM 128
#define BN 64
#define BKK 32
#define NT (HDIM / BKK)   // 32 K-steps

typedef __attribute__((ext_vector_type(8))) __bf16 bf16x8;
typedef __attribute__((ext_vector_type(8))) unsigned short u16x8;
typedef __attribute__((ext_vector_type(4))) float f32x4;

static __device__ __forceinline__ unsigned short f2b(float f) {
    __hip_bfloat16 h = __float2bfloat16(f);
    return __builtin_bit_cast(unsigned short, h);
}

static __device__ __forceinline__ void barrier_fence() {
    asm volatile("" ::: "memory");
    __builtin_amdgcn_s_barrier();
    asm volatile("" ::: "memory");
}

// One fused fp32->bf16 pack pass over weights (+ optionally x,h).
// Block ranges (256 thr x 1 float4 each):
//   [0,3072) Wih | [3072,4096) Ur | [4096,5120) Uz | [5120,6144) Un
//   [6144,14336) x | [14336,22528) h
__global__ void __launch_bounds__(256) cvt_all(
    const float* __restrict__ x, const float* __restrict__ h,
    const float* __restrict__ wih, const float* __restrict__ ur,
    const float* __restrict__ uz, const float* __restrict__ un,
    unsigned short* __restrict__ wb, unsigned short* __restrict__ urb,
    unsigned short* __restrict__ uzb, unsigned short* __restrict__ unb,
    unsigned short* __restrict__ xb, unsigned short* __restrict__ hb) {
    int b = blockIdx.x;
    const float* src; unsigned short* dst; int idx;
    if (b < 3072)       { src = wih; dst = wb;  idx = b; }
    else if (b < 4096)  { src = ur;  dst = urb; idx = b - 3072; }
    else if (b < 5120)  { src = uz;  dst = uzb; idx = b - 4096; }
    else if (b < 6144)  { src = un;  dst = unb; idx = b - 5120; }
    else if (b < 14336) { src = x;   dst = xb;  idx = b - 6144; }
    else                { src = h;   dst = hb;  idx = b - 14336; }
    int i = idx * 256 + threadIdx.x;
    float4 v = ((const float4*)src)[i];
    ushort4 o;
    o.x = f2b(v.x); o.y = f2b(v.y); o.z = f2b(v.z); o.w = f2b(v.w);
    ((ushort4*)dst)[i] = o;
}

// Fused GRU cell, double-buffered LDS + counted-vmcnt prefetch + XOR swizzle.
//   acc0 = x@Wr^T + h@Ur^T   acc1 = x@Wz^T + h@Uz^T
//   acc2 = x@Wn^T            acc3 = h@Un^T
// LDS tile layout per buffer (ushorts): xs[0,4096) hs[4096,8192) w[mi] at 8192+mi*2048.
// Swizzle: 16B slot s of row r lives at position s ^ ((r>>1)&3)  (2-way banks on read).
template<bool XHB>
__global__ void __launch_bounds__(256, 2)
gru_fused(const float* __restrict__ hg,
          const unsigned short* __restrict__ xb, const unsigned short* __restrict__ hb,
          const float* __restrict__ xg32, const float* __restrict__ hg32,
          const unsigned short* __restrict__ wih,
          const unsigned short* __restrict__ ur,
          const unsigned short* __restrict__ uz,
          const unsigned short* __restrict__ un,
          const float* __restrict__ bih, const float* __restrict__ bun,
          float* __restrict__ out) {
    __shared__ __align__(16) unsigned short smem[2][20480];

    const int tid  = threadIdx.x;
    const int lane = tid & 63;
    const int wv   = tid >> 6;
    const int wm   = wv >> 1;
    const int wn   = wv & 1;
    const int lr   = lane & 15;
    const int ls   = lane >> 4;
    const int m0   = blockIdx.y * BM;
    const int n0   = blockIdx.x * BN;

    const unsigned short* wb6[6] = {
        wih + (size_t)n0 * HDIM,
        wih + (size_t)(HDIM + n0) * HDIM,
        wih + (size_t)(2 * HDIM + n0) * HDIM,
        ur  + (size_t)n0 * HDIM,
        uz  + (size_t)n0 * HDIM,
        un  + (size_t)n0 * HDIM
    };

    // staging chunk indices (weights): chunk c covers row c>>2, swizzled-source slot
    const int wr  = tid >> 2;                       // weight row 0..63
    const int wsl = (tid & 3) ^ ((tid >> 3) & 3);   // pre-swizzled global slot

    f32x4 acc[4][4][2];
#pragma unroll
    for (int g = 0; g < 4; ++g)
#pragma unroll
        for (int mf = 0; mf < 4; ++mf)
#pragma unroll
            for (int nf = 0; nf < 2; ++nf)
                acc[g][mf][nf] = f32x4{0.f, 0.f, 0.f, 0.f};

    auto STAGE = [&](int bufi, int kt) {
        const int k0 = kt * BKK;
        unsigned short* sb = &smem[bufi][0];
        float4 fx[2][2], fh[2][2];
        if constexpr (!XHB) {
            // fp32 loads FIRST so their drain doesn't flush the gload_lds queue
#pragma unroll
            for (int half = 0; half < 2; ++half) {
                const int c2 = half * 256 + tid;
                const int r2 = c2 >> 2;
                const int sl = c2 & 3;
                const float* gx = xg32 + (size_t)(m0 + r2) * HDIM + k0 + sl * 8;
                const float* gh = hg32 + (size_t)(m0 + r2) * HDIM + k0 + sl * 8;
                fx[half][0] = ((const float4*)gx)[0];
                fx[half][1] = ((const float4*)gx)[1];
                fh[half][0] = ((const float4*)gh)[0];
                fh[half][1] = ((const float4*)gh)[1];
            }
        }
        // 6 weight tiles via global_load_lds w16 (linear LDS dest, pre-swizzled source)
#pragma unroll
        for (int mi = 0; mi < 6; ++mi) {
            const unsigned short* g = wb6[mi] + (size_t)wr * HDIM + k0 + wsl * 8;
            __builtin_amdgcn_global_load_lds(
                (const __attribute__((address_space(1))) void*)g,
                (__attribute__((address_space(3))) void*)(sb + 8192 + mi * 2048 + wv * 512),
                16, 0, 0);
        }
        if constexpr (XHB) {
#pragma unroll
            for (int half = 0; half < 2; ++half) {
                const int c2 = half * 256 + tid;
                const int r2 = c2 >> 2;
                const int sl = (c2 & 3) ^ ((c2 >> 3) & 3);
                const unsigned short* gx = xb + (size_t)(m0 + r2) * HDIM + k0 + sl * 8;
                const unsigned short* gh = hb + (size_t)(m0 + r2) * HDIM + k0 + sl * 8;
                __builtin_amdgcn_global_load_lds(
                    (const __attribute__((address_space(1))) void*)gx,
                    (__attribute__((address_space(3))) void*)(sb + half * 2048 + wv * 512),
                    16, 0, 0);
                __builtin_amdgcn_global_load_lds(
                    (const __attribute__((address_space(1))) void*)gh,
                    (__attribute__((address_space(3))) void*)(sb + 4096 + half * 2048 + wv * 512),
                    16, 0, 0);
            }
        } else {
            // convert + swizzled ds_write_b128
#pragma unroll
            for (int half = 0; half < 2; ++half) {
                const int c2 = half * 256 + tid;
                const int r2 = c2 >> 2;
                const int sp = (c2 & 3) ^ ((c2 >> 3) & 3);  // swizzled LDS position
                u16x8 px, ph;
#pragma unroll
                for (int q = 0; q < 4; ++q) {
                    px[q]     = f2b(fx[half][0][q]);
                    px[q + 4] = f2b(fx[half][1][q]);
                    ph[q]     = f2b(fh[half][0][q]);
                    ph[q + 4] = f2b(fh[half][1][q]);
                }
                *(u16x8*)(sb + r2 * 32 + sp * 8)        = px;
                *(u16x8*)(sb + 4096 + r2 * 32 + sp * 8) = ph;
            }
        }
    };

    auto COMPUTE = [&](int bufi) {
        const unsigned short* sb = &smem[bufi][0];
        const int sel = (lr >> 1) & 3;
        const int fo  = (ls ^ sel) << 3;   // swizzled 16B slot within row
        bf16x8 ax[4], ah[4];
#pragma unroll
        for (int mf = 0; mf < 4; ++mf) {
            const int row = wm * 64 + mf * 16 + lr;
            ax[mf] = *(const bf16x8*)(sb + row * 32 + fo);
            ah[mf] = *(const bf16x8*)(sb + 4096 + row * 32 + fo);
        }
#pragma unroll
        for (int mi = 0; mi < 6; ++mi) {
            const unsigned short* wt = sb + 8192 + mi * 2048;
            bf16x8 b0 = *(const bf16x8*)(wt + (wn * 32 + lr) * 32 + fo);
            bf16x8 b1 = *(const bf16x8*)(wt + (wn * 32 + 16 + lr) * 32 + fo);
            const int g = (mi == 0 || mi == 3) ? 0 : (mi == 1 || mi == 4) ? 1 : (mi == 2) ? 2 : 3;
            const bf16x8* a = (mi < 3) ? ax : ah;
#pragma unroll
            for (int mf = 0; mf < 4; ++mf) {
                acc[g][mf][0] = __builtin_amdgcn_mfma_f32_16x16x32_bf16(a[mf], b0, acc[g][mf][0], 0, 0, 0);
                acc[g][mf][1] = __builtin_amdgcn_mfma_f32_16x16x32_bf16(a[mf], b1, acc[g][mf][1], 0, 0, 0);
            }
        }
    };

    // counted-vmcnt wait: keep the 10 (or 6) just-issued loads in flight
    auto WAITN = [&]() {
        if constexpr (XHB) asm volatile("s_waitcnt vmcnt(10)" ::: "memory");
        else               asm volatile("s_waitcnt vmcnt(6) lgkmcnt(0)" ::: "memory");
    };

    STAGE(0, 0);
#pragma unroll 1
    for (int kt = 0; kt < NT - 2; kt += 2) {
        STAGE(1, kt + 1); WAITN(); barrier_fence();
        COMPUTE(0);       barrier_fence();
        STAGE(0, kt + 2); WAITN(); barrier_fence();
        COMPUTE(1);       barrier_fence();
    }
    STAGE(1, NT - 1); WAITN(); barrier_fence();
    COMPUTE(0);       barrier_fence();
    asm volatile("s_waitcnt vmcnt(0) lgkmcnt(0)" ::: "memory");
    __builtin_amdgcn_s_barrier();
    asm volatile("" ::: "memory");
    COMPUTE(1);

    // epilogue: gates + output (C/D layout: col=lane&15, row=(lane>>4)*4+reg)
#pragma unroll
    for (int nf = 0; nf < 2; ++nf) {
        const int gc = n0 + wn * 32 + nf * 16 + lr;
        const float br  = bih[gc];
        const float bz  = bih[HDIM + gc];
        const float bnx = bih[2 * HDIM + gc];
        const float bn2 = bun[gc];
#pragma unroll
        for (int mf = 0; mf < 4; ++mf) {
            const f32x4 aR = acc[0][mf][nf];
            const f32x4 aZ = acc[1][mf][nf];
            const f32x4 aX = acc[2][mf][nf];
            const f32x4 aH = acc[3][mf][nf];
#pragma unroll
            for (int rr = 0; rr < 4; ++rr) {
                const int gr = m0 + wm * 64 + mf * 16 + ls * 4 + rr;
                const float rv = 1.f / (1.f + __expf(-(aR[rr] + br)));
                const float zv = 1.f / (1.f + __expf(-(aZ[rr] + bz)));
                const float nv = tanhf(aX[rr] + bnx + rv * (aH[rr] + bn2));
                const float hv = hg[(size_t)gr * HDIM + gc];
                out[(size_t)gr * HDIM + gc] = (1.f - zv) * nv + zv * hv;
            }
        }
    }
}

extern "C" void kernel_launch(void* const* d_in, const int* in_sizes, int n_in,
                              void* d_out, int out_size, void* d_ws, size_t ws_size,
                              hipStream_t stream) {
    const float* x   = (const float*)d_in[0];
    const float* h   = (const float*)d_in[1];
    const float* Wih = (const float*)d_in[2];
    const float* bih = (const float*)d_in[3];
    const float* Ur  = (const float*)d_in[4];
    const float* Uz  = (const float*)d_in[5];
    const float* Un  = (const float*)d_in[6];
    const float* bun = (const float*)d_in[7];
    float* out = (float*)d_out;

    unsigned short* wsp  = (unsigned short*)d_ws;
    unsigned short* wihb = wsp;                       // 3M ush (6 MB)
    unsigned short* urb  = wihb + 3 * 1024 * 1024;    // 1M ush each
    unsigned short* uzb  = urb + 1024 * 1024;
    unsigned short* unb  = uzb + 1024 * 1024;
    unsigned short* xb   = unb + 1024 * 1024;         // 8M ush (16 MB)
    unsigned short* hb   = xb + 8 * 1024 * 1024;      // 8M ush (16 MB)

    const bool xhb = ws_size >= 46137344ull;          // 44 MB needed for bf16 x/h

    cvt_all<<<xhb ? 22528 : 6144, 256, 0, stream>>>(
        x, h, Wih, Ur, Uz, Un, wihb, urb, uzb, unb, xb, hb);

    dim3 grid(HDIM / BN, 8192 / BM);  // (16, 64)
    if (xhb)
        gru_fused<true><<<grid, 256, 0, stream>>>(
            h, xb, hb, nullptr, nullptr, wihb, urb, uzb, unb, bih, bun, out);
    else
        gru_fused<false><<<grid, 256, 0, stream>>>(
            h, nullptr, nullptr, x, h, wihb, urb, uzb, unb, bih, bun, out);
}